// Round 7
// baseline (466.784 us; speedup 1.0000x reference)
//
#include <hip/hip_runtime.h>
#include <hip/hip_bf16.h>

typedef float fv4 __attribute__((ext_vector_type(4)));
typedef unsigned uv4 __attribute__((ext_vector_type(4)));
using bf8   = __attribute__((ext_vector_type(8))) short;  // 8 bf16 = 4 VGPRs (MFMA A/B frag)
using f32x4 = __attribute__((ext_vector_type(4))) float;  // MFMA C/D frag

#define HDIM  64
#define NSLOT 64            // region-sum staging copies (power of 2)
#define QENT  520           // 512 channel sums + 8 counts

// round-to-nearest-even fp32 -> bf16 bits (prep path)
__device__ __forceinline__ unsigned bf16r(float f) {
    unsigned u = __float_as_uint(f);
    return (u + 0x7fffu + ((u >> 16) & 1u)) >> 16;
}

// relu(u+v) on a packed bf16 pair, round-half-up repack
__device__ __forceinline__ unsigned relu_pack(unsigned ud, unsigned vd) {
    float ul = __uint_as_float(ud << 16);
    float uh = __uint_as_float(ud & 0xffff0000u);
    float vl = __uint_as_float(vd << 16);
    float vh = __uint_as_float(vd & 0xffff0000u);
    float rl = fmaxf(ul + vl, 0.f);
    float rh = fmaxf(uh + vh, 0.f);
    unsigned pl = __float_as_uint(rl) + 0x8000u;
    unsigned ph = __float_as_uint(rh) + 0x8000u;
    return (ph & 0xffff0000u) | (pl >> 16);
}
// pack two fp32 -> bf16 pair, round-half-up
__device__ __forceinline__ unsigned pack_pair(float f0, float f1) {
    unsigned p0 = __float_as_uint(f0) + 0x8000u;
    unsigned p1 = __float_as_uint(f1) + 0x8000u;
    return (p0 >> 16) | (p1 & 0xffff0000u);
}

// ---------------------------------------------------------------------------
// prep: (a) split W2 of conv1/conv2 into transposed bf16 hi/lo  [c][j]
//       (b) combined pre-GEMM weight for conv2: Wpre[c'][d]
//       (c) zero the region-sum staging buffer (QENT x NSLOT floats)
// ---------------------------------------------------------------------------
__global__ void prep_kernel(const float* __restrict__ W2a, const float* __restrict__ W2b,
                            const float* __restrict__ W1c,
                            unsigned short* __restrict__ hiA, unsigned short* __restrict__ loA,
                            unsigned short* __restrict__ hiB, unsigned short* __restrict__ loB,
                            unsigned short* __restrict__ wph, unsigned short* __restrict__ wpl,
                            float* __restrict__ qstage)
{
    int idx = blockIdx.x * 256 + threadIdx.x;
    if (idx < QENT * NSLOT) qstage[idx] = 0.f;
    if (idx < 4096) {
        int j = idx >> 6, c = idx & 63;
        float w = W2a[idx];
        unsigned h = bf16r(w);
        unsigned l = bf16r(w - __uint_as_float(h << 16));
        hiA[c * 64 + j] = (unsigned short)h; loA[c * 64 + j] = (unsigned short)l;
        w = W2b[idx];
        h = bf16r(w);
        l = bf16r(w - __uint_as_float(h << 16));
        hiB[c * 64 + j] = (unsigned short)h; loB[c * 64 + j] = (unsigned short)l;
    }
    if (idx < 8192) {
        int d = idx & 63, cp = idx >> 6;
        float w = (cp < 64) ? (W1c[d * 64 + cp] - W1c[(d + 64) * 64 + cp])
                            : W1c[(d + 64) * 64 + (cp - 64)];
        unsigned h = bf16r(w);
        unsigned l = bf16r(w - __uint_as_float(h << 16));
        wph[cp * 64 + d] = (unsigned short)h;
        wpl[cp * 64 + d] = (unsigned short)l;
    }
}

// ---------------------------------------------------------------------------
// pre1: u = [x|pos] @ (W1a - W1b) + b1 ; v = [x|pos] @ W1b   (D = 19)
// unroll-2 over nodes with both nodes' loads hoisted (break load->use chain).
// ---------------------------------------------------------------------------
__global__ void pre1_kernel(
    const float* __restrict__ x, const float* __restrict__ pos,
    const float* __restrict__ W1, const float* __restrict__ b1,
    unsigned short* __restrict__ U, unsigned short* __restrict__ V, int N)
{
    int lane = threadIdx.x & 63;
    int gw   = (blockIdx.x * blockDim.x + threadIdx.x) >> 6;
    int tw   = (gridDim.x * blockDim.x) >> 6;

    float wd[19], wb[19];
#pragma unroll
    for (int d = 0; d < 19; ++d) {
        float a = W1[d * HDIM + lane];
        float b = W1[(d + 19) * HDIM + lane];
        wd[d] = a - b;
        wb[d] = b;
    }
    float bb = b1[lane];

    for (int n = gw; n < N; n += 2 * tw) {
        int n2 = n + tw; if (n2 >= N) n2 = n;   // clamp: benign duplicate
        fv4 hA[4], hB[4];
#pragma unroll
        for (int d4 = 0; d4 < 4; ++d4) {
            hA[d4] = __builtin_nontemporal_load((const fv4*)&x[(size_t)n  * 16 + 4 * d4]);
            hB[d4] = __builtin_nontemporal_load((const fv4*)&x[(size_t)n2 * 16 + 4 * d4]);
        }
        float pA[3], pB[3];
#pragma unroll
        for (int d = 0; d < 3; ++d) {
            pA[d] = pos[(size_t)n  * 3 + d];
            pB[d] = pos[(size_t)n2 * 3 + d];
        }
        float suA = 0.f, svA = 0.f, suB = 0.f, svB = 0.f;
#pragma unroll
        for (int d4 = 0; d4 < 4; ++d4)
#pragma unroll
            for (int k = 0; k < 4; ++k) {
                suA += hA[d4][k] * wd[4 * d4 + k];
                svA += hA[d4][k] * wb[4 * d4 + k];
                suB += hB[d4][k] * wd[4 * d4 + k];
                svB += hB[d4][k] * wb[4 * d4 + k];
            }
#pragma unroll
        for (int d = 0; d < 3; ++d) {
            suA += pA[d] * wd[16 + d];  svA += pA[d] * wb[16 + d];
            suB += pB[d] * wd[16 + d];  svB += pB[d] * wb[16 + d];
        }
        U[(size_t)n  * HDIM + lane] = (unsigned short)bf16r(suA + bb);
        V[(size_t)n  * HDIM + lane] = (unsigned short)bf16r(svA);
        U[(size_t)n2 * HDIM + lane] = (unsigned short)bf16r(suB + bb);
        V[(size_t)n2 * HDIM + lane] = (unsigned short)bf16r(svB);
    }
}

// ---------------------------------------------------------------------------
// pre_mfma (conv2 layer-1): [N x 64] @ [64 x 128] on MFMA, grid-stride with
// depth-1 prefetch of the next tile's node fragment (R6 theory: one-shot
// load->use serialization). A = Wpre (out-channels), B = 16-node tile.
// ---------------------------------------------------------------------------
__global__ __launch_bounds__(256, 2) void pre_mfma_kernel(
    const unsigned short* __restrict__ h,     // bf16 N x 64 (streaming)
    const unsigned short* __restrict__ Whi,   // bf16 [c' 0..127][d 0..63]
    const unsigned short* __restrict__ Wlo,
    const float* __restrict__ b1,
    unsigned short* __restrict__ U, unsigned short* __restrict__ V, int nTiles)
{
    int lane = threadIdx.x & 63;
    int quad = lane >> 4;
    int m    = lane & 15;
    int gw   = (blockIdx.x * blockDim.x + threadIdx.x) >> 6;
    int tw   = (gridDim.x * blockDim.x) >> 6;

    bf8 Ah[8][2], Al[8][2];              // weight frags: A[m=c'][k=d]
#pragma unroll
    for (int nt = 0; nt < 8; ++nt)
#pragma unroll
        for (int ks = 0; ks < 2; ++ks) {
            int off = (nt * 16 + m) * 64 + ks * 32 + quad * 8;
            Ah[nt][ks] = *(const bf8*)&Whi[off];
            Al[nt][ks] = *(const bf8*)&Wlo[off];
        }
    fv4 bias[4];
#pragma unroll
    for (int nt = 0; nt < 4; ++nt) bias[nt] = *(const fv4*)&b1[nt * 16 + quad * 4];

    int t = gw;
    if (t >= nTiles) return;
    size_t row = (size_t)(t * 16 + m) * HDIM;
    bf8 B0 = __builtin_nontemporal_load((const bf8*)&h[row + quad * 8]);
    bf8 B1 = __builtin_nontemporal_load((const bf8*)&h[row + 32 + quad * 8]);

    while (t < nTiles) {
        int t2 = t + tw;
        int tl = (t2 < nTiles) ? t2 : t;          // clamp: redundant reload
        size_t rowN = (size_t)(tl * 16 + m) * HDIM;
        bf8 C0 = __builtin_nontemporal_load((const bf8*)&h[rowN + quad * 8]);
        bf8 C1 = __builtin_nontemporal_load((const bf8*)&h[rowN + 32 + quad * 8]);

        f32x4 acc[8] = {{0,0,0,0},{0,0,0,0},{0,0,0,0},{0,0,0,0},
                        {0,0,0,0},{0,0,0,0},{0,0,0,0},{0,0,0,0}};
#pragma unroll
        for (int nt = 0; nt < 8; ++nt) {
            acc[nt] = __builtin_amdgcn_mfma_f32_16x16x32_bf16(Al[nt][0], B0, acc[nt], 0, 0, 0);
            acc[nt] = __builtin_amdgcn_mfma_f32_16x16x32_bf16(Ah[nt][0], B0, acc[nt], 0, 0, 0);
            acc[nt] = __builtin_amdgcn_mfma_f32_16x16x32_bf16(Al[nt][1], B1, acc[nt], 0, 0, 0);
            acc[nt] = __builtin_amdgcn_mfma_f32_16x16x32_bf16(Ah[nt][1], B1, acc[nt], 0, 0, 0);
        }

        size_t nodeRow = (size_t)(t * 16 + m) * HDIM;
#pragma unroll
        for (int nt = 0; nt < 8; ++nt) {
            f32x4 v = acc[nt];
            if (nt < 4) {
#pragma unroll
                for (int r = 0; r < 4; ++r) v[r] += bias[nt][r];
            }
            unsigned d0 = pack_pair(v[0], v[1]);
            unsigned d1 = pack_pair(v[2], v[3]);
            unsigned short* __restrict__ dst = (nt < 4) ? U : V;
            unsigned* p = (unsigned*)&dst[nodeRow + (nt & 3) * 16 + quad * 4];
            p[0] = d0;
            p[1] = d1;
        }
        B0 = C0; B1 = C1; t = t2;
    }
}

// ---------------------------------------------------------------------------
// edge_mfma: out[t][c] = relu( max_{16 edges} ( relu(u[t]+v[src]) @ W2 )[c] + b2[c] )
// Wave = 4 nodes = 64 edges. Traffic-bound (R4/R5/R6 all 82-84us, FETCH 84MB):
// NT hints on single-use streams (U rows, src) to preserve L2 for the V gather.
// FUSE=true (conv2): region-mean accumulation fused into the epilogue —
// no h2 write at all; block-level LDS partials -> 64-way staged global atomics.
// ---------------------------------------------------------------------------
template<bool FUSE>
__global__ __launch_bounds__(256, 2) void edge_mfma_kernel(
    const unsigned short* __restrict__ U, const unsigned short* __restrict__ V,
    const int* __restrict__ src,
    const unsigned short* __restrict__ Whi, const unsigned short* __restrict__ Wlo,
    const float* __restrict__ b2, unsigned short* __restrict__ out,
    const int* __restrict__ labels, float* __restrict__ qstage)
{
    __shared__ float ls[QENT];
    int tid  = threadIdx.x;
    int wave = tid >> 6;
    int lane = tid & 63;
    int quad = lane >> 4;
    int m    = lane & 15;

    if (FUSE) {
        for (int i = tid; i < QENT; i += 256) ls[i] = 0.f;
        __syncthreads();
    }

    int nodeBase  = blockIdx.x * 16 + wave * 4;
    long edgeBase = (long)nodeBase * 16;

    int sArr[4];
#pragma unroll
    for (int mt = 0; mt < 4; ++mt)
        sArr[mt] = __builtin_nontemporal_load(&src[edgeBase + mt * 16 + m]);

    int lblArr[4];
    if (FUSE) {
#pragma unroll
        for (int mt = 0; mt < 4; ++mt)
            lblArr[mt] = labels[nodeBase + mt];
    }

    // hoisted loads: V gathers (cached) + U rows (single-use -> NT)
    uv4 v0[4], v1[4], u0[4], u1[4];
#pragma unroll
    for (int mt = 0; mt < 4; ++mt) {
        size_t sRow = (size_t)sArr[mt] * HDIM;
        v0[mt] = *(const uv4*)&V[sRow + quad * 8];
        v1[mt] = *(const uv4*)&V[sRow + 32 + quad * 8];
    }
#pragma unroll
    for (int mt = 0; mt < 4; ++mt) {
        size_t tRow = (size_t)(nodeBase + mt) * HDIM;
        u0[mt] = __builtin_nontemporal_load((const uv4*)&U[tRow + quad * 8]);
        u1[mt] = __builtin_nontemporal_load((const uv4*)&U[tRow + 32 + quad * 8]);
    }

    // B frags: W2^T hi/lo (L2-hot table)
    bf8 Bh[4][2], Bl[4][2];
#pragma unroll
    for (int nt = 0; nt < 4; ++nt)
#pragma unroll
        for (int ks = 0; ks < 2; ++ks) {
            int off = (nt * 16 + m) * 64 + ks * 32 + quad * 8;
            Bh[nt][ks] = *(const bf8*)&Whi[off];
            Bl[nt][ks] = *(const bf8*)&Wlo[off];
        }
    float b2v = b2[lane];

#pragma unroll
    for (int mt = 0; mt < 4; ++mt) {
        uv4 a0, a1;
#pragma unroll
        for (int d = 0; d < 4; ++d) {
            a0[d] = relu_pack(u0[mt][d], v0[mt][d]);
            a1[d] = relu_pack(u1[mt][d], v1[mt][d]);
        }
        bf8 A0 = *(bf8*)&a0;
        bf8 A1 = *(bf8*)&a1;

        f32x4 acc[4] = {{0,0,0,0},{0,0,0,0},{0,0,0,0},{0,0,0,0}};
#pragma unroll
        for (int nt = 0; nt < 4; ++nt) {
            acc[nt] = __builtin_amdgcn_mfma_f32_16x16x32_bf16(A0, Bl[nt][0], acc[nt], 0, 0, 0);
            acc[nt] = __builtin_amdgcn_mfma_f32_16x16x32_bf16(A0, Bh[nt][0], acc[nt], 0, 0, 0);
            acc[nt] = __builtin_amdgcn_mfma_f32_16x16x32_bf16(A1, Bl[nt][1], acc[nt], 0, 0, 0);
            acc[nt] = __builtin_amdgcn_mfma_f32_16x16x32_bf16(A1, Bh[nt][1], acc[nt], 0, 0, 0);
        }

        // C layout: col=lane&15 = channel(nt*16+m), row=quad*4+r = edge
        float mx[4];
#pragma unroll
        for (int nt = 0; nt < 4; ++nt)
            mx[nt] = fmaxf(fmaxf(acc[nt][0], acc[nt][1]), fmaxf(acc[nt][2], acc[nt][3]));
#pragma unroll
        for (int nt = 0; nt < 4; ++nt) {
            mx[nt] = fmaxf(mx[nt], __shfl_xor(mx[nt], 16));
            mx[nt] = fmaxf(mx[nt], __shfl_xor(mx[nt], 32));
        }
        float val = (quad == 0) ? mx[0] : (quad == 1) ? mx[1] : (quad == 2) ? mx[2] : mx[3];
        float hv  = fmaxf(val + b2v, 0.f);   // h[node][lane]
        if (!FUSE) {
            unsigned p = (__float_as_uint(hv) + 0x8000u) >> 16;
            out[(size_t)(nodeBase + mt) * HDIM + lane] = (unsigned short)p;
        } else {
            atomicAdd(&ls[lblArr[mt] * 64 + lane], hv);   // bank = lane: conflict-free
        }
    }

    if (FUSE) {
        if (lane == 0) {
#pragma unroll
            for (int mt = 0; mt < 4; ++mt)
                atomicAdd(&ls[512 + lblArr[mt]], 1.0f);
        }
        __syncthreads();
        int slot = blockIdx.x & (NSLOT - 1);
        for (int i = tid; i < QENT; i += 256)
            atomicAdd(&qstage[i * NSLOT + slot], ls[i]);
    }
}

// ---------------------------------------------------------------------------
// tail: reduce region staging, then quotient convs (8 nodes, 32 edges) +
// global add pool + linear. Single block.
// ---------------------------------------------------------------------------
#define EQ_MAX 64
__global__ void tail_kernel(const float* __restrict__ qstage,
                            const int* __restrict__ qei, int Eq,
                            const float* __restrict__ W31, const float* __restrict__ b31,
                            const float* __restrict__ W32, const float* __restrict__ b32,
                            const float* __restrict__ W41, const float* __restrict__ b41,
                            const float* __restrict__ W42, const float* __restrict__ b42,
                            const float* __restrict__ linW, const float* __restrict__ linb,
                            float* __restrict__ out)
{
    __shared__ float qx[512], uu[512], vv[512];
    __shared__ float hr[EQ_MAX * 64], me[EQ_MAX * 64];
    __shared__ __align__(16) float W2s[64 * 64];
    __shared__ int   qes[EQ_MAX], qet[EQ_MAX];
    __shared__ float emb[64];
    __shared__ float rsum[512], rcnt[8];

    int tid = threadIdx.x;
    if (Eq > EQ_MAX) Eq = EQ_MAX;

    if (tid < Eq) { qes[tid] = qei[tid]; qet[tid] = qei[Eq + tid]; }

    // phase 0: reduce the 64-way staging
    for (int e = tid; e < QENT; e += 256) {
        float s = 0.f;
        const float* p = &qstage[e * NSLOT];
#pragma unroll
        for (int k = 0; k < NSLOT; ++k) s += p[k];
        if (e < 512) rsum[e] = s; else rcnt[e - 512] = s;
    }
    __syncthreads();
    for (int idx = tid; idx < 512; idx += 256) {
        float cc = rcnt[idx >> 6];
        qx[idx] = (cc > 0.f) ? rsum[idx] / cc : 0.f;
    }
    __syncthreads();

    for (int layer = 0; layer < 2; ++layer) {
        const float* W1p = layer ? W41 : W31;
        const float* b1p = layer ? b41 : b31;
        const float* W2p = layer ? W42 : W32;
        const float* b2p = layer ? b42 : b32;

        for (int idx = tid * 4; idx < 4096; idx += 1024)
            *(fv4*)&W2s[idx] = *(const fv4*)&W2p[idx];

        for (int idx = tid; idx < 512; idx += 256) {
            int t = idx >> 6, c = idx & 63;
            float su = 0.f, sv = 0.f;
#pragma unroll 8
            for (int d = 0; d < 64; ++d) {
                float hv = qx[t * 64 + d];
                float a = W1p[d * 64 + c];
                float b = W1p[(d + 64) * 64 + c];
                su += hv * (a - b);
                sv += hv * b;
            }
            uu[idx] = su + b1p[c];
            vv[idx] = sv;
        }
        __syncthreads();

        for (int idx = tid; idx < Eq * 64; idx += 256) {
            int e = idx >> 6, c = idx & 63;
            hr[idx] = fmaxf(uu[qet[e] * 64 + c] + vv[qes[e] * 64 + c], 0.f);
        }
        __syncthreads();

        {
            int c = tid & 63, e0 = tid >> 6;
            for (int e = e0; e < Eq; e += 4) {
                float acc = 0.f;
#pragma unroll 8
                for (int j = 0; j < 64; ++j)
                    acc += hr[e * 64 + j] * W2s[j * 64 + c];
                me[e * 64 + c] = acc;
            }
        }
        __syncthreads();

        for (int idx = tid; idx < 512; idx += 256) {
            int t = idx >> 6, c = idx & 63;
            float a = -INFINITY;
            for (int e = 0; e < Eq; ++e)
                if (qet[e] == t) a = fmaxf(a, me[e * 64 + c]);
            float vout = (a == -INFINITY) ? 0.f : (a + b2p[c]);
            qx[idx] = fmaxf(vout, 0.f);
        }
        __syncthreads();
    }

    if (tid < 64) {
        float s = 0.f;
        for (int r = 0; r < 8; ++r) s += qx[r * 64 + tid];
        emb[tid] = s;
    }
    __syncthreads();
    if (tid < 8) {
        float o = linb[tid];
        for (int c = 0; c < 64; ++c) o += emb[c] * linW[c * 8 + tid];
        out[tid] = o;
    }
}

// ---------------------------------------------------------------------------
extern "C" void kernel_launch(void* const* d_in, const int* in_sizes, int n_in,
                              void* d_out, int out_size, void* d_ws, size_t ws_size,
                              hipStream_t stream)
{
    const float* x    = (const float*)d_in[0];
    const float* pos  = (const float*)d_in[1];
    const int*   ei   = (const int*)d_in[2];
    const int*   lbl  = (const int*)d_in[3];
    const int*   qei  = (const int*)d_in[4];
    const float* W11 = (const float*)d_in[5];
    const float* b11 = (const float*)d_in[6];
    const float* W12 = (const float*)d_in[7];
    const float* b12 = (const float*)d_in[8];
    const float* W21 = (const float*)d_in[9];
    const float* b21 = (const float*)d_in[10];
    const float* W22 = (const float*)d_in[11];
    const float* b22 = (const float*)d_in[12];
    const float* W31 = (const float*)d_in[13];
    const float* b31 = (const float*)d_in[14];
    const float* W32 = (const float*)d_in[15];
    const float* b32 = (const float*)d_in[16];
    const float* W41 = (const float*)d_in[17];
    const float* b41 = (const float*)d_in[18];
    const float* W42 = (const float*)d_in[19];
    const float* b42 = (const float*)d_in[20];
    const float* linW = (const float*)d_in[21];
    const float* linb = (const float*)d_in[22];

    int N  = in_sizes[0] / 16;          // 100000
    int Eq = in_sizes[4] / 2;           // 32
    const int* src = ei;                // row 0 = src; tgt = repeat(arange(N),16)

    size_t NH = (size_t)N * HDIM;
    unsigned short* hbf = (unsigned short*)d_ws;   // bf16 N*64 (h1 only)
    unsigned short* Ub  = hbf + NH;                // bf16 N*64
    unsigned short* Vb  = Ub + NH;                 // bf16 N*64
    unsigned short* w2h1 = Vb + NH;
    unsigned short* w2l1 = w2h1 + 4096;
    unsigned short* w2h2 = w2l1 + 4096;
    unsigned short* w2l2 = w2h2 + 4096;
    unsigned short* wph  = w2l2 + 4096;            // 8192
    unsigned short* wpl  = wph + 8192;             // 8192
    float* qstage = (float*)(wpl + 8192);          // QENT*NSLOT floats

    int edgeBlocks = N / 16;            // 6250
    int nTiles     = N / 16;

    prep_kernel<<<(QENT * NSLOT + 255) / 256, 256, 0, stream>>>(
        W12, W22, W21, w2h1, w2l1, w2h2, w2l2, wph, wpl, qstage);
    // conv1
    pre1_kernel<<<2048, 256, 0, stream>>>(x, pos, W11, b11, Ub, Vb, N);
    edge_mfma_kernel<false><<<edgeBlocks, 256, 0, stream>>>(
        Ub, Vb, src, w2h1, w2l1, b12, hbf, nullptr, nullptr);
    // conv2
    pre_mfma_kernel<<<512, 256, 0, stream>>>(hbf, wph, wpl, b21, Ub, Vb, nTiles);
    edge_mfma_kernel<true><<<edgeBlocks, 256, 0, stream>>>(
        Ub, Vb, src, w2h2, w2l2, b22, nullptr, lbl, qstage);
    // quotient tail (reduces staging internally)
    tail_kernel<<<1, 256, 0, stream>>>(qstage, qei, Eq,
                                       W31, b31, W32, b32,
                                       W41, b41, W42, b42,
                                       linW, linb, (float*)d_out);
}

// Round 8
// 365.351 us; speedup vs baseline: 1.2776x; 1.2776x over previous
//
#include <hip/hip_runtime.h>
#include <hip/hip_bf16.h>

typedef float fv4 __attribute__((ext_vector_type(4)));
typedef unsigned uv4 __attribute__((ext_vector_type(4)));
typedef unsigned uv2 __attribute__((ext_vector_type(2)));
using f32x2 = __attribute__((ext_vector_type(2))) float;
using bf8   = __attribute__((ext_vector_type(8))) short;  // 8 bf16 = 4 VGPRs (MFMA A/B frag)
using f32x4 = __attribute__((ext_vector_type(4))) float;  // MFMA C/D frag

#define HDIM 64

// round-to-nearest-even fp32 -> bf16 bits (prep path)
__device__ __forceinline__ unsigned bf16r(float f) {
    unsigned u = __float_as_uint(f);
    return (u + 0x7fffu + ((u >> 16) & 1u)) >> 16;
}
__device__ __forceinline__ float bfs2f(unsigned short s) { return __uint_as_float(((unsigned)s) << 16); }

// pack two fp32 -> bf16 pair, round-half-up
__device__ __forceinline__ unsigned pack_pair(float f0, float f1) {
    unsigned p0 = __float_as_uint(f0) + 0x8000u;
    unsigned p1 = __float_as_uint(f1) + 0x8000u;
    return (p0 >> 16) | (p1 & 0xffff0000u);
}

// 4 packed fp8 e4m3 -> 4 floats (hw v_cvt_pk_f32_fp8)
__device__ __forceinline__ void fp8x4_to_f32(unsigned w, float* f) {
    f32x2 lo = __builtin_amdgcn_cvt_pk_f32_fp8((int)w, false);
    f32x2 hi = __builtin_amdgcn_cvt_pk_f32_fp8((int)w, true);
    f[0] = lo[0]; f[1] = lo[1]; f[2] = hi[0]; f[3] = hi[1];
}
// 4 floats -> packed fp8 e4m3 (hw v_cvt_pk_fp8_f32)
__device__ __forceinline__ unsigned f32x4_to_fp8(float a, float b, float c, float d) {
    int w = 0;
    w = __builtin_amdgcn_cvt_pk_fp8_f32(a, b, w, false);
    w = __builtin_amdgcn_cvt_pk_fp8_f32(c, d, w, true);
    return (unsigned)w;
}

// ---------------------------------------------------------------------------
// prep: W2 hi/lo splits (transposed), conv2 combined pre-weight, zero qsums.
// ---------------------------------------------------------------------------
__global__ void prep_kernel(const float* __restrict__ W2a, const float* __restrict__ W2b,
                            const float* __restrict__ W1c,
                            unsigned short* __restrict__ hiA, unsigned short* __restrict__ loA,
                            unsigned short* __restrict__ hiB, unsigned short* __restrict__ loB,
                            unsigned short* __restrict__ wph, unsigned short* __restrict__ wpl,
                            float* __restrict__ qsums, int* __restrict__ qcnt)
{
    int idx = blockIdx.x * 256 + threadIdx.x;
    if (idx < 512) qsums[idx] = 0.f;
    if (idx < 8)   qcnt[idx]  = 0;
    if (idx < 4096) {
        int j = idx >> 6, c = idx & 63;
        float w = W2a[idx];
        unsigned h = bf16r(w);
        unsigned l = bf16r(w - __uint_as_float(h << 16));
        hiA[c * 64 + j] = (unsigned short)h; loA[c * 64 + j] = (unsigned short)l;
        w = W2b[idx];
        h = bf16r(w);
        l = bf16r(w - __uint_as_float(h << 16));
        hiB[c * 64 + j] = (unsigned short)h; loB[c * 64 + j] = (unsigned short)l;
    }
    if (idx < 8192) {
        int d = idx & 63, cp = idx >> 6;
        float w = (cp < 64) ? (W1c[d * 64 + cp] - W1c[(d + 64) * 64 + cp])
                            : W1c[(d + 64) * 64 + (cp - 64)];
        unsigned h = bf16r(w);
        unsigned l = bf16r(w - __uint_as_float(h << 16));
        wph[cp * 64 + d] = (unsigned short)h;
        wpl[cp * 64 + d] = (unsigned short)l;
    }
}

// ---------------------------------------------------------------------------
// pre1: u = [x|pos] @ (W1a - W1b) + b1 (bf16) ; v = [x|pos] @ W1b (fp8 e4m3).
// unroll-2 over nodes, loads hoisted.
// ---------------------------------------------------------------------------
__global__ void pre1_kernel(
    const float* __restrict__ x, const float* __restrict__ pos,
    const float* __restrict__ W1, const float* __restrict__ b1,
    unsigned short* __restrict__ U, unsigned char* __restrict__ Vf8, int N)
{
    int lane = threadIdx.x & 63;
    int gw   = (blockIdx.x * blockDim.x + threadIdx.x) >> 6;
    int tw   = (gridDim.x * blockDim.x) >> 6;

    float wd[19], wb[19];
#pragma unroll
    for (int d = 0; d < 19; ++d) {
        float a = W1[d * HDIM + lane];
        float b = W1[(d + 19) * HDIM + lane];
        wd[d] = a - b;
        wb[d] = b;
    }
    float bb = b1[lane];

    for (int n = gw; n < N; n += 2 * tw) {
        int n2 = n + tw; if (n2 >= N) n2 = n;   // clamp: benign duplicate
        fv4 hA[4], hB[4];
#pragma unroll
        for (int d4 = 0; d4 < 4; ++d4) {
            hA[d4] = __builtin_nontemporal_load((const fv4*)&x[(size_t)n  * 16 + 4 * d4]);
            hB[d4] = __builtin_nontemporal_load((const fv4*)&x[(size_t)n2 * 16 + 4 * d4]);
        }
        float pA[3], pB[3];
#pragma unroll
        for (int d = 0; d < 3; ++d) {
            pA[d] = pos[(size_t)n  * 3 + d];
            pB[d] = pos[(size_t)n2 * 3 + d];
        }
        float suA = 0.f, svA = 0.f, suB = 0.f, svB = 0.f;
#pragma unroll
        for (int d4 = 0; d4 < 4; ++d4)
#pragma unroll
            for (int k = 0; k < 4; ++k) {
                suA += hA[d4][k] * wd[4 * d4 + k];
                svA += hA[d4][k] * wb[4 * d4 + k];
                suB += hB[d4][k] * wd[4 * d4 + k];
                svB += hB[d4][k] * wb[4 * d4 + k];
            }
#pragma unroll
        for (int d = 0; d < 3; ++d) {
            suA += pA[d] * wd[16 + d];  svA += pA[d] * wb[16 + d];
            suB += pB[d] * wd[16 + d];  svB += pB[d] * wb[16 + d];
        }
        U[(size_t)n  * HDIM + lane] = (unsigned short)bf16r(suA + bb);
        U[(size_t)n2 * HDIM + lane] = (unsigned short)bf16r(suB + bb);
        Vf8[(size_t)n  * HDIM + lane] =
            (unsigned char)(__builtin_amdgcn_cvt_pk_fp8_f32(svA, svA, 0, false) & 0xff);
        Vf8[(size_t)n2 * HDIM + lane] =
            (unsigned char)(__builtin_amdgcn_cvt_pk_fp8_f32(svB, svB, 0, false) & 0xff);
    }
}

// ---------------------------------------------------------------------------
// pre_mfma (conv2 layer-1): [N x 64] @ [64 x 128] on MFMA, grid-stride with
// depth-1 prefetch. A = Wpre (out-channels), B = 16-node tile.
// U out bf16; V out fp8 (4 contiguous channels -> one u32 store).
// ---------------------------------------------------------------------------
__global__ __launch_bounds__(256, 2) void pre_mfma_kernel(
    const unsigned short* __restrict__ h,     // bf16 N x 64 (streaming)
    const unsigned short* __restrict__ Whi,   // bf16 [c' 0..127][d 0..63]
    const unsigned short* __restrict__ Wlo,
    const float* __restrict__ b1,
    unsigned short* __restrict__ U, unsigned char* __restrict__ Vf8, int nTiles)
{
    int lane = threadIdx.x & 63;
    int quad = lane >> 4;
    int m    = lane & 15;
    int gw   = (blockIdx.x * blockDim.x + threadIdx.x) >> 6;
    int tw   = (gridDim.x * blockDim.x) >> 6;

    bf8 Ah[8][2], Al[8][2];              // weight frags: A[m=c'][k=d]
#pragma unroll
    for (int nt = 0; nt < 8; ++nt)
#pragma unroll
        for (int ks = 0; ks < 2; ++ks) {
            int off = (nt * 16 + m) * 64 + ks * 32 + quad * 8;
            Ah[nt][ks] = *(const bf8*)&Whi[off];
            Al[nt][ks] = *(const bf8*)&Wlo[off];
        }
    fv4 bias[4];
#pragma unroll
    for (int nt = 0; nt < 4; ++nt) bias[nt] = *(const fv4*)&b1[nt * 16 + quad * 4];

    int t = gw;
    if (t >= nTiles) return;
    size_t row = (size_t)(t * 16 + m) * HDIM;
    bf8 B0 = __builtin_nontemporal_load((const bf8*)&h[row + quad * 8]);
    bf8 B1 = __builtin_nontemporal_load((const bf8*)&h[row + 32 + quad * 8]);

    while (t < nTiles) {
        int t2 = t + tw;
        int tl = (t2 < nTiles) ? t2 : t;          // clamp: redundant reload
        size_t rowN = (size_t)(tl * 16 + m) * HDIM;
        bf8 C0 = __builtin_nontemporal_load((const bf8*)&h[rowN + quad * 8]);
        bf8 C1 = __builtin_nontemporal_load((const bf8*)&h[rowN + 32 + quad * 8]);

        f32x4 acc[8] = {{0,0,0,0},{0,0,0,0},{0,0,0,0},{0,0,0,0},
                        {0,0,0,0},{0,0,0,0},{0,0,0,0},{0,0,0,0}};
#pragma unroll
        for (int nt = 0; nt < 8; ++nt) {
            acc[nt] = __builtin_amdgcn_mfma_f32_16x16x32_bf16(Al[nt][0], B0, acc[nt], 0, 0, 0);
            acc[nt] = __builtin_amdgcn_mfma_f32_16x16x32_bf16(Ah[nt][0], B0, acc[nt], 0, 0, 0);
            acc[nt] = __builtin_amdgcn_mfma_f32_16x16x32_bf16(Al[nt][1], B1, acc[nt], 0, 0, 0);
            acc[nt] = __builtin_amdgcn_mfma_f32_16x16x32_bf16(Ah[nt][1], B1, acc[nt], 0, 0, 0);
        }

        size_t nodeRow = (size_t)(t * 16 + m) * HDIM;
#pragma unroll
        for (int nt = 0; nt < 8; ++nt) {
            f32x4 v = acc[nt];
            if (nt < 4) {
#pragma unroll
                for (int r = 0; r < 4; ++r) v[r] += bias[nt][r];
                unsigned d0 = pack_pair(v[0], v[1]);
                unsigned d1 = pack_pair(v[2], v[3]);
                unsigned* p = (unsigned*)&U[nodeRow + (nt & 3) * 16 + quad * 4];
                p[0] = d0;
                p[1] = d1;
            } else {
                unsigned w8 = f32x4_to_fp8(v[0], v[1], v[2], v[3]);
                *(unsigned*)&Vf8[nodeRow + (nt & 3) * 16 + quad * 4] = w8;
            }
        }
        B0 = C0; B1 = C1; t = t2;
    }
}

// ---------------------------------------------------------------------------
// edge_mfma: out[t][c] = relu( max_{16 edges} ( relu(u[t]+v[src]) @ W2 )[c] + b2[c] )
// Wave = 4 nodes = 64 edges, no LDS/barriers. Gather-traffic-bound
// (R4/R5/R6: 3 structures all 82-84us, FETCH 84MB) -> V stored fp8 e4m3
// (64B rows, halves the dominant cross-XCD re-fetch). bf16 MFMA after hw
// fp8 decode; U rows NT (single-use).
// ---------------------------------------------------------------------------
__global__ __launch_bounds__(256, 2) void edge_mfma_kernel(
    const unsigned short* __restrict__ U, const unsigned char* __restrict__ Vf8,
    const int* __restrict__ src,
    const unsigned short* __restrict__ Whi, const unsigned short* __restrict__ Wlo,
    const float* __restrict__ b2, unsigned short* __restrict__ out)
{
    int tid  = threadIdx.x;
    int wave = tid >> 6;
    int lane = tid & 63;
    int quad = lane >> 4;
    int m    = lane & 15;

    int nodeBase  = blockIdx.x * 16 + wave * 4;
    long edgeBase = (long)nodeBase * 16;

    int sArr[4];
#pragma unroll
    for (int mt = 0; mt < 4; ++mt)
        sArr[mt] = __builtin_nontemporal_load(&src[edgeBase + mt * 16 + m]);

    // hoisted: fp8 V gathers (8B each) + NT U rows (16B each)
    uv2 v0[4], v1[4];
    uv4 u0[4], u1[4];
#pragma unroll
    for (int mt = 0; mt < 4; ++mt) {
        size_t sRow = (size_t)sArr[mt] * HDIM;       // byte offset (64B rows)
        v0[mt] = *(const uv2*)&Vf8[sRow + quad * 8];
        v1[mt] = *(const uv2*)&Vf8[sRow + 32 + quad * 8];
    }
#pragma unroll
    for (int mt = 0; mt < 4; ++mt) {
        size_t tRow = (size_t)(nodeBase + mt) * HDIM;
        u0[mt] = __builtin_nontemporal_load((const uv4*)&U[tRow + quad * 8]);
        u1[mt] = __builtin_nontemporal_load((const uv4*)&U[tRow + 32 + quad * 8]);
    }

    // B frags: W2^T hi/lo (L2-hot table)
    bf8 Bh[4][2], Bl[4][2];
#pragma unroll
    for (int nt = 0; nt < 4; ++nt)
#pragma unroll
        for (int ks = 0; ks < 2; ++ks) {
            int off = (nt * 16 + m) * 64 + ks * 32 + quad * 8;
            Bh[nt][ks] = *(const bf8*)&Whi[off];
            Bl[nt][ks] = *(const bf8*)&Wlo[off];
        }
    float b2v = b2[lane];

#pragma unroll
    for (int mt = 0; mt < 4; ++mt) {
        float vf0[8], vf1[8];
        fp8x4_to_f32(v0[mt][0], &vf0[0]);
        fp8x4_to_f32(v0[mt][1], &vf0[4]);
        fp8x4_to_f32(v1[mt][0], &vf1[0]);
        fp8x4_to_f32(v1[mt][1], &vf1[4]);

        uv4 a0, a1;
#pragma unroll
        for (int d = 0; d < 4; ++d) {
            unsigned ud0 = u0[mt][d], ud1 = u1[mt][d];
            float r0 = fmaxf(__uint_as_float(ud0 << 16)        + vf0[2 * d],     0.f);
            float r1 = fmaxf(__uint_as_float(ud0 & 0xffff0000u) + vf0[2 * d + 1], 0.f);
            float r2 = fmaxf(__uint_as_float(ud1 << 16)        + vf1[2 * d],     0.f);
            float r3 = fmaxf(__uint_as_float(ud1 & 0xffff0000u) + vf1[2 * d + 1], 0.f);
            a0[d] = pack_pair(r0, r1);
            a1[d] = pack_pair(r2, r3);
        }
        bf8 A0 = *(bf8*)&a0;
        bf8 A1 = *(bf8*)&a1;

        f32x4 acc[4] = {{0,0,0,0},{0,0,0,0},{0,0,0,0},{0,0,0,0}};
#pragma unroll
        for (int nt = 0; nt < 4; ++nt) {
            acc[nt] = __builtin_amdgcn_mfma_f32_16x16x32_bf16(A0, Bl[nt][0], acc[nt], 0, 0, 0);
            acc[nt] = __builtin_amdgcn_mfma_f32_16x16x32_bf16(A0, Bh[nt][0], acc[nt], 0, 0, 0);
            acc[nt] = __builtin_amdgcn_mfma_f32_16x16x32_bf16(A1, Bl[nt][1], acc[nt], 0, 0, 0);
            acc[nt] = __builtin_amdgcn_mfma_f32_16x16x32_bf16(A1, Bh[nt][1], acc[nt], 0, 0, 0);
        }

        // C layout: col=lane&15 = channel(nt*16+m), row=quad*4+r = edge
        float mx[4];
#pragma unroll
        for (int nt = 0; nt < 4; ++nt)
            mx[nt] = fmaxf(fmaxf(acc[nt][0], acc[nt][1]), fmaxf(acc[nt][2], acc[nt][3]));
#pragma unroll
        for (int nt = 0; nt < 4; ++nt) {
            mx[nt] = fmaxf(mx[nt], __shfl_xor(mx[nt], 16));
            mx[nt] = fmaxf(mx[nt], __shfl_xor(mx[nt], 32));
        }
        float val = (quad == 0) ? mx[0] : (quad == 1) ? mx[1] : (quad == 2) ? mx[2] : mx[3];
        unsigned p = (__float_as_uint(fmaxf(val + b2v, 0.f)) + 0x8000u) >> 16;
        out[(size_t)(nodeBase + mt) * HDIM + lane] = (unsigned short)p;
    }
}

// ---------------------------------------------------------------------------
// region mean accumulation (bf16 input)
// ---------------------------------------------------------------------------
__global__ void region_mean_kernel(const unsigned short* __restrict__ h,
                                   const int* __restrict__ labels,
                                   float* __restrict__ qsums, int* __restrict__ qcnt, int N)
{
    __shared__ float ls[8 * 64];
    __shared__ int   lc[8];
    int tid  = threadIdx.x;
    int lane = tid & 63;
    int gw   = (blockIdx.x * blockDim.x + tid) >> 6;
    int tw   = (gridDim.x * blockDim.x) >> 6;

    float acc[8] = {0, 0, 0, 0, 0, 0, 0, 0};
    int   cnt[8] = {0, 0, 0, 0, 0, 0, 0, 0};

    for (int n = gw; n < N; n += tw) {
        int lbl = labels[n];
        float val = bfs2f(h[(size_t)n * HDIM + lane]);
#pragma unroll
        for (int r = 0; r < 8; ++r) {
            acc[r] += (lbl == r) ? val : 0.f;
            cnt[r] += (lbl == r) ? 1 : 0;
        }
    }

    if (tid < 8) lc[tid] = 0;
    for (int idx = tid; idx < 512; idx += 256) ls[idx] = 0.f;
    __syncthreads();
#pragma unroll
    for (int r = 0; r < 8; ++r) atomicAdd(&ls[r * 64 + lane], acc[r]);
    if (lane == 0)
#pragma unroll
        for (int r = 0; r < 8; ++r) atomicAdd(&lc[r], cnt[r]);
    __syncthreads();
    for (int idx = tid; idx < 512; idx += 256) atomicAdd(&qsums[idx], ls[idx]);
    if (tid < 8) atomicAdd(&qcnt[tid], lc[tid]);
}

// ---------------------------------------------------------------------------
// tail: fully parallel quotient convs (8 nodes, 32 edges) + pool + linear.
// ---------------------------------------------------------------------------
#define EQ_MAX 64
__global__ void tail_kernel(const float* __restrict__ qsums, const int* __restrict__ qcnt,
                            const int* __restrict__ qei, int Eq,
                            const float* __restrict__ W31, const float* __restrict__ b31,
                            const float* __restrict__ W32, const float* __restrict__ b32,
                            const float* __restrict__ W41, const float* __restrict__ b41,
                            const float* __restrict__ W42, const float* __restrict__ b42,
                            const float* __restrict__ linW, const float* __restrict__ linb,
                            float* __restrict__ out)
{
    __shared__ float qx[512], uu[512], vv[512];
    __shared__ float hr[EQ_MAX * 64], me[EQ_MAX * 64];
    __shared__ __align__(16) float W2s[64 * 64];
    __shared__ int   qes[EQ_MAX], qet[EQ_MAX];
    __shared__ float emb[64];

    int tid = threadIdx.x;
    if (Eq > EQ_MAX) Eq = EQ_MAX;

    if (tid < Eq) { qes[tid] = qei[tid]; qet[tid] = qei[Eq + tid]; }
    for (int idx = tid; idx < 512; idx += 256) {
        int r = idx >> 6;
        int cc = qcnt[r];
        qx[idx] = (cc > 0) ? qsums[idx] / (float)cc : 0.f;
    }
    __syncthreads();

    for (int layer = 0; layer < 2; ++layer) {
        const float* W1p = layer ? W41 : W31;
        const float* b1p = layer ? b41 : b31;
        const float* W2p = layer ? W42 : W32;
        const float* b2p = layer ? b42 : b32;

        for (int idx = tid * 4; idx < 4096; idx += 1024)
            *(fv4*)&W2s[idx] = *(const fv4*)&W2p[idx];

        for (int idx = tid; idx < 512; idx += 256) {
            int t = idx >> 6, c = idx & 63;
            float su = 0.f, sv = 0.f;
#pragma unroll 8
            for (int d = 0; d < 64; ++d) {
                float hv = qx[t * 64 + d];
                float a = W1p[d * 64 + c];
                float b = W1p[(d + 64) * 64 + c];
                su += hv * (a - b);
                sv += hv * b;
            }
            uu[idx] = su + b1p[c];
            vv[idx] = sv;
        }
        __syncthreads();

        for (int idx = tid; idx < Eq * 64; idx += 256) {
            int e = idx >> 6, c = idx & 63;
            hr[idx] = fmaxf(uu[qet[e] * 64 + c] + vv[qes[e] * 64 + c], 0.f);
        }
        __syncthreads();

        {
            int c = tid & 63, e0 = tid >> 6;
            for (int e = e0; e < Eq; e += 4) {
                float acc = 0.f;
#pragma unroll 8
                for (int j = 0; j < 64; ++j)
                    acc += hr[e * 64 + j] * W2s[j * 64 + c];
                me[e * 64 + c] = acc;
            }
        }
        __syncthreads();

        for (int idx = tid; idx < 512; idx += 256) {
            int t = idx >> 6, c = idx & 63;
            float a = -INFINITY;
            for (int e = 0; e < Eq; ++e)
                if (qet[e] == t) a = fmaxf(a, me[e * 64 + c]);
            float vout = (a == -INFINITY) ? 0.f : (a + b2p[c]);
            qx[idx] = fmaxf(vout, 0.f);
        }
        __syncthreads();
    }

    if (tid < 64) {
        float s = 0.f;
        for (int r = 0; r < 8; ++r) s += qx[r * 64 + tid];
        emb[tid] = s;
    }
    __syncthreads();
    if (tid < 8) {
        float o = linb[tid];
        for (int c = 0; c < 64; ++c) o += emb[c] * linW[c * 8 + tid];
        out[tid] = o;
    }
}

// ---------------------------------------------------------------------------
extern "C" void kernel_launch(void* const* d_in, const int* in_sizes, int n_in,
                              void* d_out, int out_size, void* d_ws, size_t ws_size,
                              hipStream_t stream)
{
    const float* x    = (const float*)d_in[0];
    const float* pos  = (const float*)d_in[1];
    const int*   ei   = (const int*)d_in[2];
    const int*   lbl  = (const int*)d_in[3];
    const int*   qei  = (const int*)d_in[4];
    const float* W11 = (const float*)d_in[5];
    const float* b11 = (const float*)d_in[6];
    const float* W12 = (const float*)d_in[7];
    const float* b12 = (const float*)d_in[8];
    const float* W21 = (const float*)d_in[9];
    const float* b21 = (const float*)d_in[10];
    const float* W22 = (const float*)d_in[11];
    const float* b22 = (const float*)d_in[12];
    const float* W31 = (const float*)d_in[13];
    const float* b31 = (const float*)d_in[14];
    const float* W32 = (const float*)d_in[15];
    const float* b32 = (const float*)d_in[16];
    const float* W41 = (const float*)d_in[17];
    const float* b41 = (const float*)d_in[18];
    const float* W42 = (const float*)d_in[19];
    const float* b42 = (const float*)d_in[20];
    const float* linW = (const float*)d_in[21];
    const float* linb = (const float*)d_in[22];

    int N  = in_sizes[0] / 16;          // 100000
    int Eq = in_sizes[4] / 2;           // 32
    const int* src = ei;                // row 0 = src; tgt = repeat(arange(N),16)

    size_t NH = (size_t)N * HDIM;
    unsigned short* hbf = (unsigned short*)d_ws;   // bf16 N*64 (h1, then h2)
    unsigned short* Ub  = hbf + NH;                // bf16 N*64
    unsigned char*  Vf8 = (unsigned char*)(Ub + NH); // fp8 N*64
    unsigned short* w2h1 = (unsigned short*)(Vf8 + NH);
    unsigned short* w2l1 = w2h1 + 4096;
    unsigned short* w2h2 = w2l1 + 4096;
    unsigned short* w2l2 = w2h2 + 4096;
    unsigned short* wph  = w2l2 + 4096;            // 8192
    unsigned short* wpl  = wph + 8192;             // 8192
    float* qsums = (float*)(wpl + 8192);
    int*   qcnt  = (int*)(qsums + 512);

    int edgeBlocks = N / 16;            // 6250
    int nTiles     = N / 16;

    prep_kernel<<<32, 256, 0, stream>>>(W12, W22, W21, w2h1, w2l1, w2h2, w2l2,
                                        wph, wpl, qsums, qcnt);
    // conv1
    pre1_kernel<<<2048, 256, 0, stream>>>(x, pos, W11, b11, Ub, Vf8, N);
    edge_mfma_kernel<<<edgeBlocks, 256, 0, stream>>>(Ub, Vf8, src, w2h1, w2l1, b12, hbf);
    // conv2
    pre_mfma_kernel<<<512, 256, 0, stream>>>(hbf, wph, wpl, b21, Ub, Vf8, nTiles);
    edge_mfma_kernel<<<edgeBlocks, 256, 0, stream>>>(Ub, Vf8, src, w2h2, w2l2, b22, hbf);
    // quotient pooling + tail
    region_mean_kernel<<<1024, 256, 0, stream>>>(hbf, lbl, qsums, qcnt, N);
    tail_kernel<<<1, 256, 0, stream>>>(qsums, qcnt, qei, Eq,
                                       W31, b31, W32, b32,
                                       W41, b41, W42, b42,
                                       linW, linb, (float*)d_out);
}